// Round 2
// baseline (324.092 us; speedup 1.0000x reference)
//
#include <hip/hip_runtime.h>

// RandomTimeMask: out[n,c,l] = x[n,c,l] if ((l - starts[n,c]) mod L) >= L/4 else 0
// N=128, C=12, L=32768, mask_len=8192. Memory-bound elementwise streaming.
//
// R4 == R3 resubmitted verbatim (R3 bench died on container acquisition, not
// on the kernel — no counters produced, hypothesis untested).
//
// R3 changes vs R2:
//  - starts[row] made PROVABLY block-uniform: row = blockIdx.x >> 4 (16 blocks
//    of 512 float4 per 8192-float4 row). Compiler can now emit a scalar s_load
//    instead of a per-lane global_load_dword + vmcnt wait at block start.
//  - Loads switched from non-temporal to regular: x (201 MB) fits in the
//    256 MB Infinity Cache; nt loads guaranteed an HBM round-trip every
//    iteration. Stores remain non-temporal (pure streaming output, and we do
//    NOT want 201 MB of writes evicting x from LLC).
//  - Masked-run skip kept: mask is one 8192-elem (32 KB) circular run per row,
//    so the all-4-masked branch is wave-uniform except at run edges and saves
//    ~25% of input fetch (~50 MB).

typedef float f4 __attribute__((ext_vector_type(4)));

__global__ __launch_bounds__(256) void RandomTimeMask_kernel(
    const f4* __restrict__ x,
    const int* __restrict__ starts,
    f4* __restrict__ out)
{
    const int LM   = 32767;  // L - 1
    const int MLEN = 8192;   // mask length

    // 8192 float4 per row, 512 float4 per block -> 16 blocks per row.
    // row depends only on blockIdx -> uniform -> scalar load of starts.
    const int row  = blockIdx.x >> 4;
    const int s    = starts[row];
    const int col0 = ((blockIdx.x & 15) << 9) + threadIdx.x;  // float4-col in row
    const int base4 = blockIdx.x * 512 + threadIdx.x;         // global float4 idx

#pragma unroll
    for (int j = 0; j < 2; ++j) {
        const int idx4 = base4 + j * 256;
        const int b    = ((col0 + j * 256) << 2) - s;  // elem offset minus start

        const bool k0 = ((b    ) & LM) >= MLEN;
        const bool k1 = ((b + 1) & LM) >= MLEN;
        const bool k2 = ((b + 2) & LM) >= MLEN;
        const bool k3 = ((b + 3) & LM) >= MLEN;

        f4 v = {0.0f, 0.0f, 0.0f, 0.0f};
        if (k0 | k1 | k2 | k3) {                 // wave-uniform except at run edges
            v = x[idx4];                         // regular load: may hit / allocate LLC
            v[0] = k0 ? v[0] : 0.0f;
            v[1] = k1 ? v[1] : 0.0f;
            v[2] = k2 ? v[2] : 0.0f;
            v[3] = k3 ? v[3] : 0.0f;
        }
        __builtin_nontemporal_store(v, &out[idx4]);
    }
}

extern "C" void kernel_launch(void* const* d_in, const int* in_sizes, int n_in,
                              void* d_out, int out_size, void* d_ws, size_t ws_size,
                              hipStream_t stream) {
    const f4*  x      = (const f4*)d_in[0];
    const int* starts = (const int*)d_in[1];
    f4*        out    = (f4*)d_out;

    int total4 = out_size >> 2;      // 12,582,912 float4
    int block  = 256;
    int grid   = total4 / 512;       // 24,576 blocks, 2 float4/thread

    RandomTimeMask_kernel<<<grid, block, 0, stream>>>(x, starts, out);
}

// Round 3
// 309.279 us; speedup vs baseline: 1.0479x; 1.0479x over previous
//
#include <hip/hip_runtime.h>

// RandomTimeMask: out[n,c,l] = x[n,c,l] if ((l - starts[n,c]) mod L) >= L/4 else 0
// N=128, C=12, L=32768, mask_len=8192. Memory-bound elementwise streaming.
//
// R5 = R2 load policy + R3 scalar-starts.
//  - NT loads restored: R3's regular loads cost +18 us. Mechanism: the
//    harness's 805 MB poison fill leaves the 256 MB LLC full of DIRTY lines
//    every iteration; caching loads allocate ~151 MB of x-lines -> each
//    allocation evicts a dirty line -> ~150 MB of write-back traffic lands
//    inside the kernel window (+~23 us at 6.5 TB/s, observed +18). NT loads
//    never allocate -> no eviction write-backs. x can never be LLC-resident
//    anyway (fill thrashes it), so caching loads have zero upside here.
//  - starts[row] stays PROVABLY block-uniform: row = blockIdx.x >> 4
//    (16 blocks of 512 float4 per 8192-float4 row) -> scalar s_load, no
//    per-lane VMEM load + vmcnt wait at block start.
//  - Masked-run skip kept: mask is one 8192-elem (32 KB) circular run per
//    row -> the all-4-masked branch is wave-uniform except at the two run
//    edges; saves ~25% of input fetch (~50 MB).

typedef float f4 __attribute__((ext_vector_type(4)));

__global__ __launch_bounds__(256) void RandomTimeMask_kernel(
    const f4* __restrict__ x,
    const int* __restrict__ starts,
    f4* __restrict__ out)
{
    const int LM   = 32767;  // L - 1
    const int MLEN = 8192;   // mask length

    // 8192 float4 per row, 512 float4 per block -> 16 blocks per row.
    // row depends only on blockIdx -> uniform -> scalar load of starts.
    const int row  = blockIdx.x >> 4;
    const int s    = starts[row];
    const int col0 = ((blockIdx.x & 15) << 9) + threadIdx.x;  // float4-col in row
    const int base4 = blockIdx.x * 512 + threadIdx.x;         // global float4 idx

#pragma unroll
    for (int j = 0; j < 2; ++j) {
        const int idx4 = base4 + j * 256;
        const int b    = ((col0 + j * 256) << 2) - s;  // elem offset minus start

        const bool k0 = ((b    ) & LM) >= MLEN;
        const bool k1 = ((b + 1) & LM) >= MLEN;
        const bool k2 = ((b + 2) & LM) >= MLEN;
        const bool k3 = ((b + 3) & LM) >= MLEN;

        f4 v = {0.0f, 0.0f, 0.0f, 0.0f};
        if (k0 | k1 | k2 | k3) {                 // wave-uniform except at run edges
            v = __builtin_nontemporal_load(&x[idx4]);
            v[0] = k0 ? v[0] : 0.0f;
            v[1] = k1 ? v[1] : 0.0f;
            v[2] = k2 ? v[2] : 0.0f;
            v[3] = k3 ? v[3] : 0.0f;
        }
        __builtin_nontemporal_store(v, &out[idx4]);
    }
}

extern "C" void kernel_launch(void* const* d_in, const int* in_sizes, int n_in,
                              void* d_out, int out_size, void* d_ws, size_t ws_size,
                              hipStream_t stream) {
    const f4*  x      = (const f4*)d_in[0];
    const int* starts = (const int*)d_in[1];
    f4*        out    = (f4*)d_out;

    int total4 = out_size >> 2;      // 12,582,912 float4
    int block  = 256;
    int grid   = total4 / 512;       // 24,576 blocks, 2 float4/thread

    RandomTimeMask_kernel<<<grid, block, 0, stream>>>(x, starts, out);
}